// Round 13
// baseline (419.646 us; speedup 1.0000x reference)
//
#include <hip/hip_runtime.h>
#include <hip/hip_bf16.h>
#include <math.h>

// Problem constants
#define B_  512
#define XD_ 32768
#define PD_ 512
#define D_  64
#define H_  128
#define G1_ 1024

typedef __attribute__((ext_vector_type(8))) short short8v;
typedef __attribute__((ext_vector_type(4))) float floatx4;

__device__ __forceinline__ float eluf(float v) { return v > 0.f ? v : expm1f(v); }

// Truncation split: hi = c with low 16 mantissa bits zeroed (exact residual),
// lo = bf16-trunc of residual. Packed pairwise with v_perm_b32 (~3 ops/value).
__device__ __forceinline__ void split8t(const float* c, short8v& h, short8v& l) {
    unsigned hu[8], lu[8];
    #pragma unroll
    for (int j = 0; j < 8; j++) {
        unsigned u = __float_as_uint(c[j]);
        hu[j] = u & 0xFFFF0000u;
        float res = c[j] - __uint_as_float(hu[j]);
        lu[j] = __float_as_uint(res);
    }
    uint4 hp, lp;
    hp.x = __builtin_amdgcn_perm(hu[1], hu[0], 0x07060302u);
    hp.y = __builtin_amdgcn_perm(hu[3], hu[2], 0x07060302u);
    hp.z = __builtin_amdgcn_perm(hu[5], hu[4], 0x07060302u);
    hp.w = __builtin_amdgcn_perm(hu[7], hu[6], 0x07060302u);
    lp.x = __builtin_amdgcn_perm(lu[1], lu[0], 0x07060302u);
    lp.y = __builtin_amdgcn_perm(lu[3], lu[2], 0x07060302u);
    lp.z = __builtin_amdgcn_perm(lu[5], lu[4], 0x07060302u);
    lp.w = __builtin_amdgcn_perm(lu[7], lu[6], 0x07060302u);
    h = __builtin_bit_cast(short8v, hp);
    l = __builtin_bit_cast(short8v, lp);
}

// ---------------------------------------------------------------------------
// K0: transpose+split x[512,32768] -> xh/xl planes, layout [XD/8][B][8] ushort.
// grid (512, 8), 256 thr. LDS-tiled: coalesced reads + coalesced writes.
// ---------------------------------------------------------------------------
__global__ __launch_bounds__(256) void k_trs(const float* __restrict__ x,
                                             ushort* __restrict__ xh,
                                             ushort* __restrict__ xl) {
    __shared__ float tile[64][65];
    const int k0 = blockIdx.x * 64;
    const int m0 = blockIdx.y * 64;
    const int t = threadIdx.x;
    const int c = t & 63, rr = t >> 6;   // read: col c, row group rr
    #pragma unroll
    for (int i = 0; i < 16; i++) {
        int r = i * 4 + rr;
        tile[r][c] = x[(size_t)(m0 + r) * XD_ + k0 + c];
    }
    __syncthreads();
    const int m = t & 63;
    const int kq = t >> 6;               // 0..3
    #pragma unroll
    for (int i = 0; i < 2; i++) {
        int kg = kq * 2 + i;             // 0..7
        float cc[8];
        #pragma unroll
        for (int j = 0; j < 8; j++) cc[j] = tile[m][kg * 8 + j];
        short8v h, l; split8t(cc, h, l);
        size_t off = ((size_t)((k0 >> 3) + kg) * B_ + m0 + m) * 8;
        *(short8v*)(xh + off) = h;
        *(short8v*)(xl + off) = l;
    }
}

// ---------------------------------------------------------------------------
// K0b: pre-split a stacked weight  src[64][R][128] -> hi/lo planes in the
// staged-chunk layout [d][R/8][128][8]: chunk (d,kg,col) = rows kg*8..+7 of
// column col. Removes the 8-16x redundant fused split from k_hwh_t (Wh) and
// k_heads (W2). grid (64 d, R/16), 256 thr: kg_local = t>>7, col = t&127.
// Reads coalesced across threads (fixed row j, 128 consecutive cols).
// ---------------------------------------------------------------------------
__global__ __launch_bounds__(256) void k_wsplit(const float* __restrict__ src,
                                                ushort* __restrict__ dh,
                                                ushort* __restrict__ dl,
                                                int R) {
    const int d = blockIdx.x;
    const int r0 = blockIdx.y * 16;
    const int t = threadIdx.x;
    const int kgl = t >> 7;          // 0..1
    const int col = t & 127;
    const float* p = src + (size_t)d * R * 128 + (size_t)(r0 + kgl * 8) * 128 + col;
    float c[8];
    #pragma unroll
    for (int j = 0; j < 8; j++) c[j] = p[(size_t)j * 128];
    short8v h, l; split8t(c, h, l);
    size_t off = (((size_t)d * (R >> 3) + (r0 >> 3) + kgl) * 128 + col) * 8;
    *(short8v*)(dh + off) = h;
    *(short8v*)(dl + off) = l;
}

// ---------------------------------------------------------------------------
// K1: split-bf16 MFMA GEMM from pre-split planes (proven structure). Tile
// 128x128 (4 waves 2x2, acc[4][4]), BK=32, 1D grid 512 = 2 blocks/CU.
// T1 XCD swizzle (verified: FETCH 353->104 MB): wid = (bid%8)*64 + bid/8.
// Double-buffered LDS (64 KB), one raw lgkmcnt barrier per K-step; 2-step
// register prefetch flies across the barrier.
// ---------------------------------------------------------------------------
__global__ __launch_bounds__(256, 2) void k_gemm1t(const ushort* __restrict__ xh,
                                                   const ushort* __restrict__ xl,
                                                   const float* __restrict__ Wg1,
                                                   float* __restrict__ part,
                                                   int KS) {
    __shared__ ushort Ah[2][4 * 128 * 8], Al[2][4 * 128 * 8];
    __shared__ ushort Bh[2][4 * 128 * 8], Bl[2][4 * 128 * 8];
    const int wid = (blockIdx.x & 7) * 64 + (blockIdx.x >> 3);  // bijective (512%8==0)
    const int nt = wid & 7, mt = (wid >> 3) & 3, ks = wid >> 5;
    const int t = threadIdx.x;
    const int w = t >> 6, lane = t & 63;
    const int q = lane >> 4, l15 = lane & 15;
    const int wr = w >> 1, wc = w & 1;      // wave -> 64x64 quadrant
    const int q4 = t >> 6, pr = t & 63;     // staging: k-group, row/col id
    const int k0 = ks * KS;

    const size_t aoff = (((size_t)(k0 >> 3) + q4) * B_ + mt * 128 + pr) * 8;
    const ushort* Agh = xh + aoff;
    const ushort* Agl = xl + aoff;
    const float*  Bg  = Wg1 + (size_t)(k0 + q4 * 8) * G1_ + nt * 128 + pr * 2;

    floatx4 acc[4][4];
    #pragma unroll
    for (int i = 0; i < 4; i++)
        #pragma unroll
        for (int j = 0; j < 4; j++) acc[i][j] = (floatx4){0.f, 0.f, 0.f, 0.f};

    uint4 pAh0, pAh1, pAl0, pAl1;
    float2 pb[8];

    auto loadT = [&](int kt) {
        size_t o = (size_t)kt * B_;
        pAh0 = *(const uint4*)(Agh + o);
        pAh1 = *(const uint4*)(Agh + o + 512);
        pAl0 = *(const uint4*)(Agl + o);
        pAl1 = *(const uint4*)(Agl + o + 512);
        const float* p = Bg + (size_t)kt * G1_;
        #pragma unroll
        for (int kk = 0; kk < 8; kk++) pb[kk] = *(const float2*)(p + (size_t)kk * G1_);
    };

    auto stage = [&](int buf) {
        float c0[8], c1[8];
        #pragma unroll
        for (int kk = 0; kk < 8; kk++) { c0[kk] = pb[kk].x; c1[kk] = pb[kk].y; }
        short8v bh0, bl0, bh1, bl1;
        split8t(c0, bh0, bl0); split8t(c1, bh1, bl1);
        int n0 = pr * 2;
        int i0 = (q4 * 128 + (n0 ^ q4)) * 8;
        int i1 = (q4 * 128 + ((n0 + 1) ^ q4)) * 8;
        *(short8v*)&Bh[buf][i0] = bh0; *(short8v*)&Bl[buf][i0] = bl0;
        *(short8v*)&Bh[buf][i1] = bh1; *(short8v*)&Bl[buf][i1] = bl1;
        int ia = (q4 * 128 + (pr ^ q4)) * 8;
        *(uint4*)&Ah[buf][ia] = pAh0;
        *(uint4*)&Al[buf][ia] = pAl0;
        *(uint4*)&Ah[buf][ia + 512] = pAh1;
        *(uint4*)&Al[buf][ia + 512] = pAl1;
    };

    auto mma = [&](int buf) {
        short8v af[4], alf[4], bf[4], blf[4];
        #pragma unroll
        for (int i = 0; i < 4; i++) {
            int m = wr * 64 + i * 16 + l15;
            int idx = (q * 128 + (m ^ q)) * 8;
            af[i]  = *(const short8v*)&Ah[buf][idx];
            alf[i] = *(const short8v*)&Al[buf][idx];
        }
        #pragma unroll
        for (int j = 0; j < 4; j++) {
            int n = wc * 64 + j * 16 + l15;
            int idx = (q * 128 + (n ^ q)) * 8;
            bf[j]  = *(const short8v*)&Bh[buf][idx];
            blf[j] = *(const short8v*)&Bl[buf][idx];
        }
        #pragma unroll
        for (int i = 0; i < 4; i++)
            #pragma unroll
            for (int j = 0; j < 4; j++) {
                acc[i][j] = __builtin_amdgcn_mfma_f32_16x16x32_bf16(af[i],  bf[j],  acc[i][j], 0, 0, 0);
                acc[i][j] = __builtin_amdgcn_mfma_f32_16x16x32_bf16(af[i],  blf[j], acc[i][j], 0, 0, 0);
                acc[i][j] = __builtin_amdgcn_mfma_f32_16x16x32_bf16(alf[i], bf[j],  acc[i][j], 0, 0, 0);
            }
    };

    loadT(0);
    stage(0);
    loadT(32);
    asm volatile("s_waitcnt lgkmcnt(0)" ::: "memory");
    __builtin_amdgcn_s_barrier();

    const int NT = KS >> 5;
    for (int it = 0; it < NT - 1; it++) {
        const int cur = it & 1;
        stage(cur ^ 1);
        if (it + 2 < NT) loadT((it + 2) * 32);
        mma(cur);
        asm volatile("s_waitcnt lgkmcnt(0)" ::: "memory");
        __builtin_amdgcn_s_barrier();
    }
    mma((NT - 1) & 1);

    float* P = part + (size_t)ks * (B_ * G1_) + (size_t)(mt * 128) * G1_ + nt * 128;
    #pragma unroll
    for (int i = 0; i < 4; i++)
        #pragma unroll
        for (int j = 0; j < 4; j++) {
            int col = wc * 64 + j * 16 + l15;
            #pragma unroll
            for (int r = 0; r < 4; r++) {
                int row = wr * 64 + i * 16 + q * 4 + r;
                P[(size_t)row * G1_ + col] = acc[i][j][r];
            }
        }
}

// ---------------------------------------------------------------------------
// K1 (fallback, small workspace): fused gather version reading x directly.
// ---------------------------------------------------------------------------
__global__ __launch_bounds__(256, 2) void k_gemm1m(const float* __restrict__ x,
                                                   const float* __restrict__ Wg1,
                                                   float* __restrict__ part,
                                                   int KS) {
    __shared__ ushort Ah[4 * 128 * 8], Al[4 * 128 * 8];
    __shared__ ushort Bh[4 * 128 * 8], Bl[4 * 128 * 8];
    const int nt = blockIdx.x, mt = blockIdx.y, ks = blockIdx.z;
    const int t = threadIdx.x;
    const int w = t >> 6, lane = t & 63;
    const int q = lane >> 4, l15 = lane & 15;
    const int wr = w >> 1, wc = w & 1;
    const int kbB = t >> 6, nb = t & 63;
    const int mA = t & 127, kbA = t >> 7;
    const int k0 = ks * KS;

    const float* Ag = x + (size_t)(mt * 128 + mA) * XD_ + k0 + kbA * 8;
    const float* Bg = Wg1 + (size_t)(k0 + kbB * 8) * G1_ + nt * 128 + nb * 2;

    floatx4 acc[4][4];
    #pragma unroll
    for (int i = 0; i < 4; i++)
        #pragma unroll
        for (int j = 0; j < 4; j++) acc[i][j] = (floatx4){0.f, 0.f, 0.f, 0.f};

    float4 pa0 = *(const float4*)(Ag);
    float4 pa1 = *(const float4*)(Ag + 4);
    float4 pa2 = *(const float4*)(Ag + 16);
    float4 pa3 = *(const float4*)(Ag + 20);
    float2 pb[8];
    #pragma unroll
    for (int kk = 0; kk < 8; kk++) pb[kk] = *(const float2*)(Bg + (size_t)kk * G1_);

    for (int kt = 0; kt < KS; kt += 32) {
        float cA0[8] = {pa0.x, pa0.y, pa0.z, pa0.w, pa1.x, pa1.y, pa1.z, pa1.w};
        float cA1[8] = {pa2.x, pa2.y, pa2.z, pa2.w, pa3.x, pa3.y, pa3.z, pa3.w};
        float c0[8], c1[8];
        #pragma unroll
        for (int kk = 0; kk < 8; kk++) { c0[kk] = pb[kk].x; c1[kk] = pb[kk].y; }
        short8v ah0, al0, ah1, al1, bh0, bl0, bh1, bl1;
        split8t(cA0, ah0, al0);
        split8t(cA1, ah1, al1);
        split8t(c0, bh0, bl0);
        split8t(c1, bh1, bl1);
        if (kt + 32 < KS) {
            pa0 = *(const float4*)(Ag + kt + 32);
            pa1 = *(const float4*)(Ag + kt + 36);
            pa2 = *(const float4*)(Ag + kt + 48);
            pa3 = *(const float4*)(Ag + kt + 52);
            const float* p = Bg + (size_t)(kt + 32) * G1_;
            #pragma unroll
            for (int kk = 0; kk < 8; kk++) pb[kk] = *(const float2*)(p + (size_t)kk * G1_);
        }
        {
            int ia0 = (kbA * 128 + (mA ^ kbA)) * 8;
            int ia1 = ((kbA + 2) * 128 + (mA ^ (kbA + 2))) * 8;
            *(short8v*)&Ah[ia0] = ah0; *(short8v*)&Al[ia0] = al0;
            *(short8v*)&Ah[ia1] = ah1; *(short8v*)&Al[ia1] = al1;
            int n0i = nb * 2;
            int i0 = (kbB * 128 + (n0i ^ kbB)) * 8;
            int i1 = (kbB * 128 + ((n0i + 1) ^ kbB)) * 8;
            *(short8v*)&Bh[i0] = bh0; *(short8v*)&Bl[i0] = bl0;
            *(short8v*)&Bh[i1] = bh1; *(short8v*)&Bl[i1] = bl1;
        }
        __syncthreads();
        short8v af[4], alf[4], bf[4], blf[4];
        #pragma unroll
        for (int i = 0; i < 4; i++) {
            int m = wr * 64 + i * 16 + l15;
            int idx = (q * 128 + (m ^ q)) * 8;
            af[i]  = *(const short8v*)&Ah[idx];
            alf[i] = *(const short8v*)&Al[idx];
        }
        #pragma unroll
        for (int j = 0; j < 4; j++) {
            int n = wc * 64 + j * 16 + l15;
            int idx = (q * 128 + (n ^ q)) * 8;
            bf[j]  = *(const short8v*)&Bh[idx];
            blf[j] = *(const short8v*)&Bl[idx];
        }
        #pragma unroll
        for (int i = 0; i < 4; i++)
            #pragma unroll
            for (int j = 0; j < 4; j++) {
                acc[i][j] = __builtin_amdgcn_mfma_f32_16x16x32_bf16(af[i],  bf[j],  acc[i][j], 0, 0, 0);
                acc[i][j] = __builtin_amdgcn_mfma_f32_16x16x32_bf16(af[i],  blf[j], acc[i][j], 0, 0, 0);
                acc[i][j] = __builtin_amdgcn_mfma_f32_16x16x32_bf16(alf[i], bf[j],  acc[i][j], 0, 0, 0);
            }
        __syncthreads();
    }
    float* P = part + (size_t)ks * (B_ * G1_) + (size_t)(mt * 128) * G1_ + nt * 128;
    #pragma unroll
    for (int i = 0; i < 4; i++)
        #pragma unroll
        for (int j = 0; j < 4; j++) {
            int col = wc * 64 + j * 16 + l15;
            #pragma unroll
            for (int r = 0; r < 4; r++) {
                int row = wr * 64 + i * 16 + q * 4 + r;
                P[(size_t)row * G1_ + col] = acc[i][j][r];
            }
        }
}

// K1b: reduce nparts split-K partials + bias + elu -> G as bf16 hi/lo planes
__global__ __launch_bounds__(256) void k_red1(const float* __restrict__ part,
                                              const float* __restrict__ bg1,
                                              ushort* __restrict__ Gh,
                                              ushort* __restrict__ Gl,
                                              int nparts) {
    int idx = (blockIdx.x * 256 + threadIdx.x) * 8;  // 524288 total / 8
    const int S = B_ * G1_;
    float c[8] = {};
    for (int k = 0; k < nparts; k++) {
        const float* p = part + (size_t)k * S + idx;
        float4 v0 = *(const float4*)p, v1 = *(const float4*)(p + 4);
        c[0] += v0.x; c[1] += v0.y; c[2] += v0.z; c[3] += v0.w;
        c[4] += v1.x; c[5] += v1.y; c[6] += v1.z; c[7] += v1.w;
    }
    int cb = idx & (G1_ - 1);
    float4 b0 = *(const float4*)(bg1 + cb), b1v = *(const float4*)(bg1 + cb + 4);
    c[0] = eluf(c[0] + b0.x); c[1] = eluf(c[1] + b0.y);
    c[2] = eluf(c[2] + b0.z); c[3] = eluf(c[3] + b0.w);
    c[4] = eluf(c[4] + b1v.x); c[5] = eluf(c[5] + b1v.y);
    c[6] = eluf(c[6] + b1v.z); c[7] = eluf(c[7] + b1v.w);
    short8v h, l; split8t(c, h, l);
    *(short8v*)(Gh + idx) = h;
    *(short8v*)(Gl + idx) = l;
}

// ---------------------------------------------------------------------------
// K2: part2[ks] = G[512,1024] @ Wg2[1024,512] slice — split-bf16 MFMA.
// 1D grid 512 with T1 XCD swizzle. dbuf + register prefetch + single raw
// lgkmcnt barrier per K-step.
// ---------------------------------------------------------------------------
__global__ __launch_bounds__(256, 2) void k_gemm2m(const ushort* __restrict__ Gh,
                                                   const ushort* __restrict__ Gl,
                                                   const float* __restrict__ Wg2,
                                                   float* __restrict__ part2) {
    __shared__ ushort Ah[2][4 * 64 * 8], Al[2][4 * 64 * 8];   // 4 KB each buf
    __shared__ ushort Bh[2][4 * 64 * 8], Bl[2][4 * 64 * 8];
    const int wid = (blockIdx.x & 7) * 64 + (blockIdx.x >> 3);
    const int nt = wid & 7, mt = (wid >> 3) & 7, ks = wid >> 6;
    const int t = threadIdx.x;
    const int w = t >> 6, lane = t & 63;
    const int q = lane >> 4, l15 = lane & 15;
    const int kb = (t >> 4) & 3;
    const int rb = (t & 15) | (w << 4);
    const int k0 = ks * 128;
    const int cB = t & 63, g = t >> 6;

    floatx4 acc[4];
    #pragma unroll
    for (int i = 0; i < 4; i++) acc[i] = (floatx4){0.f, 0.f, 0.f, 0.f};

    uint4 pAh, pAl;
    float cb8[8];

    auto loadT = [&](int kt) {
        const ushort* pH = Gh + (size_t)(mt * 64 + rb) * G1_ + k0 + kt + kb * 8;
        const ushort* pL = Gl + (size_t)(mt * 64 + rb) * G1_ + k0 + kt + kb * 8;
        pAh = *(const uint4*)pH;
        pAl = *(const uint4*)pL;
        const float* p = Wg2 + (size_t)(k0 + kt + g * 8) * PD_ + nt * 64 + cB;
        #pragma unroll
        for (int kk = 0; kk < 8; kk++) cb8[kk] = p[(size_t)kk * PD_];
    };

    auto stage = [&](int buf) {
        int ia = (kb * 64 + (rb ^ kb)) * 8;
        *(uint4*)&Ah[buf][ia] = pAh;
        *(uint4*)&Al[buf][ia] = pAl;
        short8v h, l; split8t(cb8, h, l);
        int ib = (g * 64 + (cB ^ g)) * 8;
        *(short8v*)&Bh[buf][ib] = h;
        *(short8v*)&Bl[buf][ib] = l;
    };

    auto mma = [&](int buf) {
        short8v af[4], alf[4], bf, blf;
        #pragma unroll
        for (int i = 0; i < 4; i++) {
            int m = i * 16 + l15;
            int idx = (q * 64 + (m ^ q)) * 8;
            af[i]  = *(const short8v*)&Ah[buf][idx];
            alf[i] = *(const short8v*)&Al[buf][idx];
        }
        {
            int n = w * 16 + l15;
            int idx = (q * 64 + (n ^ q)) * 8;
            bf  = *(const short8v*)&Bh[buf][idx];
            blf = *(const short8v*)&Bl[buf][idx];
        }
        #pragma unroll
        for (int i = 0; i < 4; i++) {
            acc[i] = __builtin_amdgcn_mfma_f32_16x16x32_bf16(af[i],  bf,  acc[i], 0, 0, 0);
            acc[i] = __builtin_amdgcn_mfma_f32_16x16x32_bf16(af[i],  blf, acc[i], 0, 0, 0);
            acc[i] = __builtin_amdgcn_mfma_f32_16x16x32_bf16(alf[i], bf,  acc[i], 0, 0, 0);
        }
    };

    loadT(0);
    stage(0);
    loadT(32);
    asm volatile("s_waitcnt lgkmcnt(0)" ::: "memory");
    __builtin_amdgcn_s_barrier();

    for (int it = 0; it < 3; it++) {
        const int cur = it & 1;
        stage(cur ^ 1);
        if (it + 2 < 4) loadT((it + 2) * 32);
        mma(cur);
        asm volatile("s_waitcnt lgkmcnt(0)" ::: "memory");
        __builtin_amdgcn_s_barrier();
    }
    mma(1);

    float* P = part2 + (size_t)ks * (B_ * PD_) + (size_t)(mt * 64) * PD_ + nt * 64;
    #pragma unroll
    for (int i = 0; i < 4; i++) {
        int col = w * 16 + l15;
        #pragma unroll
        for (int r = 0; r < 4; r++) {
            int row = i * 16 + q * 4 + r;
            P[(size_t)row * PD_ + col] = acc[i][r];
        }
    }
}

// K2b: reduce 8 partials + bias + elu -> h as bf16 hi/lo planes
__global__ __launch_bounds__(256) void k_red2(const float* __restrict__ part2,
                                              const float* __restrict__ bg2,
                                              ushort* __restrict__ hh,
                                              ushort* __restrict__ hl) {
    int idx = (blockIdx.x * 256 + threadIdx.x) * 8;
    const int S = B_ * PD_;
    float c[8] = {};
    #pragma unroll
    for (int k = 0; k < 8; k++) {
        const float* p = part2 + (size_t)k * S + idx;
        float4 v0 = *(const float4*)p, v1 = *(const float4*)(p + 4);
        c[0] += v0.x; c[1] += v0.y; c[2] += v0.z; c[3] += v0.w;
        c[4] += v1.x; c[5] += v1.y; c[6] += v1.z; c[7] += v1.w;
    }
    int cb = idx & (PD_ - 1);
    float4 b0 = *(const float4*)(bg2 + cb), b1v = *(const float4*)(bg2 + cb + 4);
    c[0] = eluf(c[0] + b0.x); c[1] = eluf(c[1] + b0.y);
    c[2] = eluf(c[2] + b0.z); c[3] = eluf(c[3] + b0.w);
    c[4] = eluf(c[4] + b1v.x); c[5] = eluf(c[5] + b1v.y);
    c[6] = eluf(c[6] + b1v.z); c[7] = eluf(c[7] + b1v.w);
    short8v h, l; split8t(c, h, l);
    *(short8v*)(hh + idx) = h;
    *(short8v*)(hl + idx) = l;
}

// ---------------------------------------------------------------------------
// K3: hWh[b,d,h] = sum_p h[b,p] * Wh[d,p,h] — split-bf16 MFMA, tile 64x128,
// grid (64 d, 8 mt) = 512 blocks = 2/CU (flat%8 = d%8 -> L2 reuse of the
// pre-split Wh planes). B staging = pure uint4 copy of whh/whl (chunk layout
// [d][kg][col][8]); A pure copy. dbuf + single raw lgkmcnt barrier.
// ---------------------------------------------------------------------------
__global__ __launch_bounds__(256, 2) void k_hwh_t(const ushort* __restrict__ hh,
                                                  const ushort* __restrict__ hl,
                                                  const ushort* __restrict__ whh,
                                                  const ushort* __restrict__ whl,
                                                  float* __restrict__ hWh) {
    __shared__ ushort Ah[2][4 * 64 * 8], Al[2][4 * 64 * 8];
    __shared__ ushort Bh[2][4 * 128 * 8], Bl[2][4 * 128 * 8];
    const int d = blockIdx.x, mt = blockIdx.y;
    const int t = threadIdx.x;
    const int w = t >> 6, lane = t & 63;
    const int q = lane >> 4, l15 = lane & 15;
    const int kb = (t >> 4) & 3;
    const int rb = (t & 15) | (w << 4);
    const int kgB = t >> 6, pr = t & 63;

    const ushort* AgH = hh + (size_t)(mt * 64 + rb) * PD_ + kb * 8;
    const ushort* AgL = hl + (size_t)(mt * 64 + rb) * PD_ + kb * 8;
    // Wh chunk base for (d, kg = kgB, col = pr*2)
    const ushort* BgH = whh + (((size_t)d * 64 + kgB) * 128 + pr * 2) * 8;
    const ushort* BgL = whl + (((size_t)d * 64 + kgB) * 128 + pr * 2) * 8;

    floatx4 acc[4][2];
    #pragma unroll
    for (int i = 0; i < 4; i++)
        #pragma unroll
        for (int j = 0; j < 2; j++) acc[i][j] = (floatx4){0.f, 0.f, 0.f, 0.f};

    uint4 pah, pal, pBh0, pBh1, pBl0, pBl1;

    auto loadT = [&](int kt) {
        pah = *(const uint4*)(AgH + kt);
        pal = *(const uint4*)(AgL + kt);
        size_t o = (size_t)(kt >> 3) * 128 * 8;   // kg advance: kt/8 chunks of 128*8
        pBh0 = *(const uint4*)(BgH + o);
        pBh1 = *(const uint4*)(BgH + o + 8);
        pBl0 = *(const uint4*)(BgL + o);
        pBl1 = *(const uint4*)(BgL + o + 8);
    };

    auto stage = [&](int buf) {
        int n0 = pr * 2;
        int i0 = (kgB * 128 + (n0 ^ kgB)) * 8;
        int i1 = (kgB * 128 + ((n0 + 1) ^ kgB)) * 8;
        *(uint4*)&Bh[buf][i0] = pBh0; *(uint4*)&Bl[buf][i0] = pBl0;
        *(uint4*)&Bh[buf][i1] = pBh1; *(uint4*)&Bl[buf][i1] = pBl1;
        int ia = (kb * 64 + (rb ^ kb)) * 8;
        *(uint4*)&Ah[buf][ia] = pah;
        *(uint4*)&Al[buf][ia] = pal;
    };

    auto mma = [&](int buf) {
        short8v af[4], alf[4], bf[2], blf[2];
        #pragma unroll
        for (int i = 0; i < 4; i++) {
            int m = i * 16 + l15;
            int idx = (q * 64 + (m ^ q)) * 8;
            af[i]  = *(const short8v*)&Ah[buf][idx];
            alf[i] = *(const short8v*)&Al[buf][idx];
        }
        #pragma unroll
        for (int j = 0; j < 2; j++) {
            int n = w * 32 + j * 16 + l15;
            int idx = (q * 128 + (n ^ q)) * 8;
            bf[j]  = *(const short8v*)&Bh[buf][idx];
            blf[j] = *(const short8v*)&Bl[buf][idx];
        }
        #pragma unroll
        for (int i = 0; i < 4; i++)
            #pragma unroll
            for (int j = 0; j < 2; j++) {
                acc[i][j] = __builtin_amdgcn_mfma_f32_16x16x32_bf16(af[i],  bf[j],  acc[i][j], 0, 0, 0);
                acc[i][j] = __builtin_amdgcn_mfma_f32_16x16x32_bf16(af[i],  blf[j], acc[i][j], 0, 0, 0);
                acc[i][j] = __builtin_amdgcn_mfma_f32_16x16x32_bf16(alf[i], bf[j],  acc[i][j], 0, 0, 0);
            }
    };

    loadT(0);
    stage(0);
    loadT(32);
    asm volatile("s_waitcnt lgkmcnt(0)" ::: "memory");
    __builtin_amdgcn_s_barrier();

    const int NT = PD_ >> 5;               // 16
    for (int it = 0; it < NT - 1; it++) {
        const int cur = it & 1;
        stage(cur ^ 1);
        if (it + 2 < NT) loadT((it + 2) * 32);
        mma(cur);
        asm volatile("s_waitcnt lgkmcnt(0)" ::: "memory");
        __builtin_amdgcn_s_barrier();
    }
    mma((NT - 1) & 1);

    #pragma unroll
    for (int i = 0; i < 4; i++)
        #pragma unroll
        for (int j = 0; j < 2; j++) {
            int col = w * 32 + j * 16 + l15;
            #pragma unroll
            for (int r = 0; r < 4; r++) {
                int row = i * 16 + q * 4 + r;
                int b = mt * 64 + row;
                hWh[(size_t)b * (D_ * H_) + d * H_ + col] = acc[i][j][r];
            }
        }
}

// ---------------------------------------------------------------------------
// K4: heads — split-bf16 MFMA. grid (64 d, 8 chunk), 2 passes FUSED per
// block (round-12 pass-split regressed +5 us: reverted). W2 staging = pure
// uint4 copies from pre-split planes w2h/w2l. flat%8 = d%8 -> W2/plane data
// L2-local. dbuf + single raw lgkmcnt barrier per kt2. sred aliases A1h.
// ---------------------------------------------------------------------------
__global__ __launch_bounds__(256, 2) void k_heads(const float* __restrict__ hWh,
                                                  const float* __restrict__ z,
                                                  const int* __restrict__ perm,
                                                  const float* __restrict__ Wz,
                                                  const float* __restrict__ b1,
                                                  const ushort* __restrict__ w2h,
                                                  const ushort* __restrict__ w2l,
                                                  const float* __restrict__ b2,
                                                  const float* __restrict__ W3,
                                                  const float* __restrict__ b3,
                                                  float* __restrict__ jpart,
                                                  float* __restrict__ epart) {
    const int d = blockIdx.x;       // 0..63
    const int chunk = blockIdx.y;   // 0..7
    const int t = threadIdx.x;
    const int b0 = chunk * 64;
    __shared__ ushort A1h[16 * 64 * 8];       // 16 KB (aliased as sred)
    __shared__ ushort A1l[16 * 64 * 8];       // 16 KB
    __shared__ ushort B2h[2][4 * 128 * 8];    // 8 KB each buf
    __shared__ ushort B2l[2][4 * 128 * 8];    // 8 KB each buf
    __shared__ float  sq[4][64];              // 1 KB
    float* sred = (float*)A1h;                // [64][64]

    const int w = t >> 6, lane = t & 63;
    const int q = lane >> 4, l15 = lane & 15;
    const int kb = (t >> 4) & 3;
    const int rb = (t & 15) | (w << 4);

    const float* Wzd = Wz + d * H_;
    const float* b1d = b1 + d * H_;
    const float* b2d = b2 + d * H_;
    const float* W3d = W3 + d * H_;
    // W2 chunk base for (d, kg = kb, col = rb*2); kt2 advances 4 chunks
    const ushort* W2H = w2h + (((size_t)d * 16 + kb) * 128 + rb * 2) * 8;
    const ushort* W2L = w2l + (((size_t)d * 16 + kb) * 128 + rb * 2) * 8;

    uint4 pWh0, pWh1, pWl0, pWl1;
    auto loadW2 = [&](int kt2) {
        size_t o = (size_t)kt2 * 4 * 128 * 8;
        pWh0 = *(const uint4*)(W2H + o);
        pWh1 = *(const uint4*)(W2H + o + 8);
        pWl0 = *(const uint4*)(W2L + o);
        pWl1 = *(const uint4*)(W2L + o + 8);
    };
    auto stageB = [&](int buf) {
        int n0i = rb * 2;
        int i0 = (kb * 128 + (n0i ^ kb)) * 8;
        int i1 = (kb * 128 + ((n0i + 1) ^ kb)) * 8;
        *(uint4*)&B2h[buf][i0] = pWh0; *(uint4*)&B2l[buf][i0] = pWl0;
        *(uint4*)&B2h[buf][i1] = pWh1; *(uint4*)&B2l[buf][i1] = pWl1;
    };

    float result0 = 0.f, result1 = 0.f;
    for (int pass = 0; pass < 2; pass++) {
        // ---- build a1 (split) into A-fragment LDS layout
        {
            int i = t >> 2;
            int kt = t & 3;
            int h0 = kt * 32;
            int bb = b0 + i;
            int src = (pass == 0) ? bb : perm[bb];
            float zv = z[bb * D_ + d];
            const float* hrow = hWh + (size_t)src * (D_ * H_) + d * H_;
            #pragma unroll
            for (int kq = 0; kq < 4; kq++) {
                float c[8];
                int kbase = h0 + kq * 8;
                float4 v0 = *(const float4*)(hrow + kbase);
                float4 v1 = *(const float4*)(hrow + kbase + 4);
                float4 w0 = *(const float4*)(Wzd + kbase);
                float4 w1 = *(const float4*)(Wzd + kbase + 4);
                float4 x0 = *(const float4*)(b1d + kbase);
                float4 x1 = *(const float4*)(b1d + kbase + 4);
                c[0] = eluf(v0.x + zv * w0.x + x0.x);
                c[1] = eluf(v0.y + zv * w0.y + x0.y);
                c[2] = eluf(v0.z + zv * w0.z + x0.z);
                c[3] = eluf(v0.w + zv * w0.w + x0.w);
                c[4] = eluf(v1.x + zv * w1.x + x1.x);
                c[5] = eluf(v1.y + zv * w1.y + x1.y);
                c[6] = eluf(v1.z + zv * w1.z + x1.z);
                c[7] = eluf(v1.w + zv * w1.w + x1.w);
                short8v hv, lv; split8t(c, hv, lv);
                int idx = ((kt * 4 + kq) * 64 + (i ^ kq)) * 8;
                *(short8v*)&A1h[idx] = hv;
                *(short8v*)&A1l[idx] = lv;
            }
        }
        // ---- K pipeline prologue: stage kt2=0, prefetch kt2=1
        loadW2(0);
        stageB(0);
        loadW2(1);
        asm volatile("s_waitcnt lgkmcnt(0)" ::: "memory");
        __builtin_amdgcn_s_barrier();

        floatx4 acc[4][2];
        #pragma unroll
        for (int i = 0; i < 4; i++)
            #pragma unroll
            for (int j = 0; j < 2; j++) acc[i][j] = (floatx4){0.f, 0.f, 0.f, 0.f};

        auto mmaP = [&](int buf, int kt2) {
            short8v af[4], alf[4], bf[2], blf[2];
            #pragma unroll
            for (int i = 0; i < 4; i++) {
                int m = i * 16 + l15;
                int idx = ((kt2 * 4 + q) * 64 + (m ^ q)) * 8;
                af[i]  = *(const short8v*)&A1h[idx];
                alf[i] = *(const short8v*)&A1l[idx];
            }
            #pragma unroll
            for (int j = 0; j < 2; j++) {
                int n = w * 32 + j * 16 + l15;
                int idx = (q * 128 + (n ^ q)) * 8;
                bf[j]  = *(const short8v*)&B2h[buf][idx];
                blf[j] = *(const short8v*)&B2l[buf][idx];
            }
            #pragma unroll
            for (int i = 0; i < 4; i++)
                #pragma unroll
                for (int j = 0; j < 2; j++) {
                    acc[i][j] = __builtin_amdgcn_mfma_f32_16x16x32_bf16(af[i],  bf[j],  acc[i][j], 0, 0, 0);
                    acc[i][j] = __builtin_amdgcn_mfma_f32_16x16x32_bf16(af[i],  blf[j], acc[i][j], 0, 0, 0);
                    acc[i][j] = __builtin_amdgcn_mfma_f32_16x16x32_bf16(alf[i], bf[j],  acc[i][j], 0, 0, 0);
                }
        };

        for (int kt2 = 0; kt2 < 3; kt2++) {
            const int cur = kt2 & 1;
            stageB(cur ^ 1);                  // stage kt2+1
            if (kt2 + 2 < 4) loadW2(kt2 + 2);
            mmaP(cur, kt2);
            asm volatile("s_waitcnt lgkmcnt(0)" ::: "memory");
            __builtin_amdgcn_s_barrier();
        }
        mmaP(1, 3);
        __syncthreads();   // all frag reads (incl. A1h) done before sred writes

        // ---- epilogue: a2 = elu(acc + b2), partial score = sum a2*W3
        #pragma unroll
        for (int i = 0; i < 4; i++) {
            #pragma unroll
            for (int r = 0; r < 4; r++) {
                int b = i * 16 + q * 4 + r;
                float s = 0.f;
                #pragma unroll
                for (int j = 0; j < 2; j++) {
                    int col = w * 32 + j * 16 + l15;
                    float a2v = eluf(acc[i][j][r] + b2d[col]);
                    s = fmaf(a2v, W3d[col], s);
                }
                sred[b * 64 + w * 16 + l15] = s;
            }
        }
        __syncthreads();
        // parallel quarter-row sums: thread t -> row t&63, quarter t>>6
        {
            int rrow = t & 63, qd = t >> 6;
            const float4* rp = (const float4*)&sred[rrow * 64 + qd * 16];
            float ps = 0.f;
            #pragma unroll
            for (int c = 0; c < 4; c++) {
                float4 v = rp[c];
                ps += v.x + v.y + v.z + v.w;
            }
            sq[qd][rrow] = ps;
        }
        __syncthreads();
        float val = 0.f;
        if (t < 64) {
            float s = b3[d] + sq[0][t] + sq[1][t] + sq[2][t] + sq[3][t];
            val = (pass == 0) ? s : expf(s);
            #pragma unroll
            for (int off = 32; off > 0; off >>= 1)
                val += __shfl_down(val, off, 64);
        }
        if (t == 0) { if (pass == 0) result0 = val; else result1 = val; }
        __syncthreads();   // protect sred/A1 before next pass rebuilds
    }
    if (t == 0) {
        jpart[d * 8 + chunk] = result0;
        epart[d * 8 + chunk] = result1;
    }
}

// ---------------------------------------------------------------------------
// Fallback variants (small workspace): fused-split hwh / heads (round-11).
// ---------------------------------------------------------------------------
__global__ __launch_bounds__(256, 2) void k_hwh_f(const ushort* __restrict__ hh,
                                                  const ushort* __restrict__ hl,
                                                  const float* __restrict__ Wh,
                                                  float* __restrict__ hWh) {
    __shared__ ushort Ah[2][4 * 64 * 8], Al[2][4 * 64 * 8];
    __shared__ ushort Bh[2][4 * 128 * 8], Bl[2][4 * 128 * 8];
    const int d = blockIdx.x, mt = blockIdx.y;
    const int t = threadIdx.x;
    const int w = t >> 6, lane = t & 63;
    const int q = lane >> 4, l15 = lane & 15;
    const int kb = (t >> 4) & 3;
    const int rb = (t & 15) | (w << 4);
    const int kgB = t >> 6, pr = t & 63;

    const ushort* AgH = hh + (size_t)(mt * 64 + rb) * PD_ + kb * 8;
    const ushort* AgL = hl + (size_t)(mt * 64 + rb) * PD_ + kb * 8;
    const float* Bg = Wh + (size_t)d * (PD_ * H_) + (size_t)(kgB * 8) * H_ + pr * 2;

    floatx4 acc[4][2];
    #pragma unroll
    for (int i = 0; i < 4; i++)
        #pragma unroll
        for (int j = 0; j < 2; j++) acc[i][j] = (floatx4){0.f, 0.f, 0.f, 0.f};

    uint4 pah, pal;
    float2 pb[8];

    auto loadT = [&](int kt) {
        pah = *(const uint4*)(AgH + kt);
        pal = *(const uint4*)(AgL + kt);
        const float* p = Bg + (size_t)kt * H_;
        #pragma unroll
        for (int kk = 0; kk < 8; kk++) pb[kk] = *(const float2*)(p + (size_t)kk * H_);
    };

    auto stage = [&](int buf) {
        float c0[8], c1[8];
        #pragma unroll
        for (int kk = 0; kk < 8; kk++) { c0[kk] = pb[kk].x; c1[kk] = pb[kk].y; }
        short8v bh0, bl0, bh1, bl1;
        split8t(c0, bh0, bl0); split8t(c1, bh1, bl1);
        int n0 = pr * 2;
        int i0 = (kgB * 128 + (n0 ^ kgB)) * 8;
        int i1 = (kgB * 128 + ((n0 + 1) ^ kgB)) * 8;
        *(short8v*)&Bh[buf][i0] = bh0; *(short8v*)&Bl[buf][i0] = bl0;
        *(short8v*)&Bh[buf][i1] = bh1; *(short8v*)&Bl[buf][i1] = bl1;
        int ia = (kb * 64 + (rb ^ kb)) * 8;
        *(uint4*)&Ah[buf][ia] = pah;
        *(uint4*)&Al[buf][ia] = pal;
    };

    auto mma = [&](int buf) {
        short8v af[4], alf[4], bf[2], blf[2];
        #pragma unroll
        for (int i = 0; i < 4; i++) {
            int m = i * 16 + l15;
            int idx = (q * 64 + (m ^ q)) * 8;
            af[i]  = *(const short8v*)&Ah[buf][idx];
            alf[i] = *(const short8v*)&Al[buf][idx];
        }
        #pragma unroll
        for (int j = 0; j < 2; j++) {
            int n = w * 32 + j * 16 + l15;
            int idx = (q * 128 + (n ^ q)) * 8;
            bf[j]  = *(const short8v*)&Bh[buf][idx];
            blf[j] = *(const short8v*)&Bl[buf][idx];
        }
        #pragma unroll
        for (int i = 0; i < 4; i++)
            #pragma unroll
            for (int j = 0; j < 2; j++) {
                acc[i][j] = __builtin_amdgcn_mfma_f32_16x16x32_bf16(af[i],  bf[j],  acc[i][j], 0, 0, 0);
                acc[i][j] = __builtin_amdgcn_mfma_f32_16x16x32_bf16(af[i],  blf[j], acc[i][j], 0, 0, 0);
                acc[i][j] = __builtin_amdgcn_mfma_f32_16x16x32_bf16(alf[i], bf[j],  acc[i][j], 0, 0, 0);
            }
    };

    loadT(0);
    stage(0);
    loadT(32);
    asm volatile("s_waitcnt lgkmcnt(0)" ::: "memory");
    __builtin_amdgcn_s_barrier();

    const int NT = PD_ >> 5;
    for (int it = 0; it < NT - 1; it++) {
        const int cur = it & 1;
        stage(cur ^ 1);
        if (it + 2 < NT) loadT((it + 2) * 32);
        mma(cur);
        asm volatile("s_waitcnt lgkmcnt(0)" ::: "memory");
        __builtin_amdgcn_s_barrier();
    }
    mma((NT - 1) & 1);

    #pragma unroll
    for (int i = 0; i < 4; i++)
        #pragma unroll
        for (int j = 0; j < 2; j++) {
            int col = w * 32 + j * 16 + l15;
            #pragma unroll
            for (int r = 0; r < 4; r++) {
                int row = i * 16 + q * 4 + r;
                int b = mt * 64 + row;
                hWh[(size_t)b * (D_ * H_) + d * H_ + col] = acc[i][j][r];
            }
        }
}

__global__ __launch_bounds__(256, 2) void k_heads_f(const float* __restrict__ hWh,
                                                    const float* __restrict__ z,
                                                    const int* __restrict__ perm,
                                                    const float* __restrict__ Wz,
                                                    const float* __restrict__ b1,
                                                    const float* __restrict__ W2,
                                                    const float* __restrict__ b2,
                                                    const float* __restrict__ W3,
                                                    const float* __restrict__ b3,
                                                    float* __restrict__ jpart,
                                                    float* __restrict__ epart) {
    const int d = blockIdx.x;
    const int chunk = blockIdx.y;
    const int t = threadIdx.x;
    const int b0 = chunk * 64;
    __shared__ ushort A1h[16 * 64 * 8];
    __shared__ ushort A1l[16 * 64 * 8];
    __shared__ ushort B2h[2][4 * 128 * 8];
    __shared__ ushort B2l[2][4 * 128 * 8];
    __shared__ float  sq[4][64];
    float* sred = (float*)A1h;

    const int w = t >> 6, lane = t & 63;
    const int q = lane >> 4, l15 = lane & 15;
    const int kb = (t >> 4) & 3;
    const int rb = (t & 15) | (w << 4);

    const float* W2d = W2 + (size_t)d * H_ * H_;
    const float* Wzd = Wz + d * H_;
    const float* b1d = b1 + d * H_;
    const float* b2d = b2 + d * H_;
    const float* W3d = W3 + d * H_;

    float2 pbW[8];
    auto loadW2 = [&](int kt2) {
        const float* p = W2d + (size_t)(kt2 * 32 + kb * 8) * H_ + rb * 2;
        #pragma unroll
        for (int kk = 0; kk < 8; kk++) pbW[kk] = *(const float2*)(p + (size_t)kk * H_);
    };
    auto stageB = [&](int buf) {
        float c0[8], c1[8];
        #pragma unroll
        for (int kk = 0; kk < 8; kk++) { c0[kk] = pbW[kk].x; c1[kk] = pbW[kk].y; }
        short8v h0v, l0v, h1v, l1v;
        split8t(c0, h0v, l0v);
        split8t(c1, h1v, l1v);
        int n0i = rb * 2;
        int i0 = (kb * 128 + (n0i ^ kb)) * 8;
        int i1 = (kb * 128 + ((n0i + 1) ^ kb)) * 8;
        *(short8v*)&B2h[buf][i0] = h0v; *(short8v*)&B2l[buf][i0] = l0v;
        *(short8v*)&B2h[buf][i1] = h1v; *(short8v*)&B2l[buf][i1] = l1v;
    };

    float result0 = 0.f, result1 = 0.f;
    for (int pass = 0; pass < 2; pass++) {
        {
            int i = t >> 2;
            int kt = t & 3;
            int h0 = kt * 32;
            int bb = b0 + i;
            int src = (pass == 0) ? bb : perm[bb];
            float zv = z[bb * D_ + d];
            const float* hrow = hWh + (size_t)src * (D_ * H_) + d * H_;
            #pragma unroll
            for (int kq = 0; kq < 4; kq++) {
                float c[8];
                int kbase = h0 + kq * 8;
                float4 v0 = *(const float4*)(hrow + kbase);
                float4 v1 = *(const float4*)(hrow + kbase + 4);
                float4 w0 = *(const float4*)(Wzd + kbase);
                float4 w1 = *(const float4*)(Wzd + kbase + 4);
                float4 x0 = *(const float4*)(b1d + kbase);
                float4 x1 = *(const float4*)(b1d + kbase + 4);
                c[0] = eluf(v0.x + zv * w0.x + x0.x);
                c[1] = eluf(v0.y + zv * w0.y + x0.y);
                c[2] = eluf(v0.z + zv * w0.z + x0.z);
                c[3] = eluf(v0.w + zv * w0.w + x0.w);
                c[4] = eluf(v1.x + zv * w1.x + x1.x);
                c[5] = eluf(v1.y + zv * w1.y + x1.y);
                c[6] = eluf(v1.z + zv * w1.z + x1.z);
                c[7] = eluf(v1.w + zv * w1.w + x1.w);
                short8v hv, lv; split8t(c, hv, lv);
                int idx = ((kt * 4 + kq) * 64 + (i ^ kq)) * 8;
                *(short8v*)&A1h[idx] = hv;
                *(short8v*)&A1l[idx] = lv;
            }
        }
        loadW2(0);
        stageB(0);
        loadW2(1);
        asm volatile("s_waitcnt lgkmcnt(0)" ::: "memory");
        __builtin_amdgcn_s_barrier();

        floatx4 acc[4][2];
        #pragma unroll
        for (int i = 0; i < 4; i++)
            #pragma unroll
            for (int j = 0; j < 2; j++) acc[i][j] = (floatx4){0.f, 0.f, 0.f, 0.f};

        auto mmaP = [&](int buf, int kt2) {
            short8v af[4], alf[4], bf[2], blf[2];
            #pragma unroll
            for (int i = 0; i < 4; i++) {
                int m = i * 16 + l15;
                int idx = ((kt2 * 4 + q) * 64 + (m ^ q)) * 8;
                af[i]  = *(const short8v*)&A1h[idx];
                alf[i] = *(const short8v*)&A1l[idx];
            }
            #pragma unroll
            for (int j = 0; j < 2; j++) {
                int n = w * 32 + j * 16 + l15;
                int idx = (q * 128 + (n ^ q)) * 8;
                bf[j]  = *(const short8v*)&B2h[buf][idx];
                blf[j] = *(const short8v*)&B2l[buf][idx];
            }
            #pragma unroll
            for (int i = 0; i < 4; i++)
                #pragma unroll
                for (int j = 0; j < 2; j++) {
                    acc[i][j] = __builtin_amdgcn_mfma_f32_16x16x32_bf16(af[i],  bf[j],  acc[i][j], 0, 0, 0);
                    acc[i][j] = __builtin_amdgcn_mfma_f32_16x16x32_bf16(af[i],  blf[j], acc[i][j], 0, 0, 0);
                    acc[i][j] = __builtin_amdgcn_mfma_f32_16x16x32_bf16(alf[i], bf[j],  acc[i][j], 0, 0, 0);
                }
        };

        for (int kt2 = 0; kt2 < 3; kt2++) {
            const int cur = kt2 & 1;
            stageB(cur ^ 1);
            if (kt2 + 2 < 4) loadW2(kt2 + 2);
            mmaP(cur, kt2);
            asm volatile("s_waitcnt lgkmcnt(0)" ::: "memory");
            __builtin_amdgcn_s_barrier();
        }
        mmaP(1, 3);
        __syncthreads();

        #pragma unroll
        for (int i = 0; i < 4; i++) {
            #pragma unroll
            for (int r = 0; r < 4; r++) {
                int b = i * 16 + q * 4 + r;
                float s = 0.f;
                #pragma unroll
                for (int j = 0; j < 2; j++) {
                    int col = w * 32 + j * 16 + l15;
                    float a2v = eluf(acc[i][j][r] + b2d[col]);
                    s = fmaf(a2v, W3d[col], s);
                }
                sred[b * 64 + w * 16 + l15] = s;
            }
        }
        __syncthreads();
        {
            int rrow = t & 63, qd = t >> 6;
            const float4* rp = (const float4*)&sred[rrow * 64 + qd * 16];
            float ps = 0.f;
            #pragma unroll
            for (int c = 0; c < 4; c++) {
                float4 v = rp[c];
                ps += v.x + v.y + v.z + v.w;
            }
            sq[qd][rrow] = ps;
        }
        __syncthreads();
        float val = 0.f;
        if (t < 64) {
            float s = b3[d] + sq[0][t] + sq[1][t] + sq[2][t] + sq[3][t];
            val = (pass == 0) ? s : expf(s);
            #pragma unroll
            for (int off = 32; off > 0; off >>= 1)
                val += __shfl_down(val, off, 64);
        }
        if (t == 0) { if (pass == 0) result0 = val; else result1 = val; }
        __syncthreads();
    }
    if (t == 0) {
        jpart[d * 8 + chunk] = result0;
        epart[d * 8 + chunk] = result1;
    }
}

// K5: final scalar. 1 block, 64 threads (one per d).
__global__ void k_final(const float* __restrict__ jpart,
                        const float* __restrict__ epart,
                        float* __restrict__ out) {
    int t = threadIdx.x;
    float mj = 0.f, me = 0.f;
    #pragma unroll
    for (int c = 0; c < 8; c++) { mj += jpart[t * 8 + c]; me += epart[t * 8 + c]; }
    mj *= (1.f / 512.f);
    me *= (1.f / 512.f);
    float mi = mj - logf(me);
    #pragma unroll
    for (int off = 32; off > 0; off >>= 1) mi += __shfl_down(mi, off, 64);
    if (t == 0) out[0] = -mi * (1.f / 64.f);
}

extern "C" void kernel_launch(void* const* d_in, const int* in_sizes, int n_in,
                              void* d_out, int out_size, void* d_ws, size_t ws_size,
                              hipStream_t stream) {
    const float* x   = (const float*)d_in[0];
    const float* z   = (const float*)d_in[1];
    const int*  perm = (const int*)d_in[2];
    const float* Wg1 = (const float*)d_in[3];
    const float* bg1 = (const float*)d_in[4];
    const float* Wg2 = (const float*)d_in[5];
    const float* bg2 = (const float*)d_in[6];
    const float* Wh  = (const float*)d_in[7];
    const float* Wz  = (const float*)d_in[8];
    const float* b1  = (const float*)d_in[9];
    const float* W2  = (const float*)d_in[10];
    const float* b2  = (const float*)d_in[11];
    const float* W3  = (const float*)d_in[12];
    const float* b3  = (const float*)d_in[13];
    float* out = (float*)d_out;

    char* base = (char*)d_ws;
    const size_t PART_SLICE = (size_t)B_ * G1_ * sizeof(float);   // 2 MB

    // Layout: part(16x2MB) | xh(32MB) | xl(32MB) | Gh/Gl(2MB) | hh/hl(1MB) |
    // jp/ep(4KB) | whh/whl(16.8MB) | w2h/w2l(4.2MB)  => ~120 MB
    const size_t NEW_NEED = 125833216ull;

    if (ws_size >= NEW_NEED) {
        float* part  = (float*)base;                       // 32 MB (16 slices)
        ushort* xh   = (ushort*)(base + 33554432);         // 32 MB
        ushort* xl   = (ushort*)(base + 67108864);         // 32 MB
        float* hWh   = (float*)base;                       // overlaps dead part
        float* part2 = (float*)(base + 16777216);
        ushort* Gh   = (ushort*)(base + 100663296);
        ushort* Gl   = Gh + 524288;
        ushort* hh   = (ushort*)(base + 102760448);
        ushort* hl   = hh + 262144;
        float* jpart = (float*)(base + 103809024);
        float* epart = jpart + 512;
        ushort* whh  = (ushort*)(base + 104857600);        // 8.4 MB
        ushort* whl  = (ushort*)(base + 113246208);        // 8.4 MB
        ushort* w2h  = (ushort*)(base + 121634816);        // 2.1 MB
        ushort* w2l  = (ushort*)(base + 123731968);        // 2.1 MB

        k_wsplit<<<dim3(64, 32), 256, 0, stream>>>(Wh, whh, whl, PD_);
        k_wsplit<<<dim3(64, 8),  256, 0, stream>>>(W2, w2h, w2l, H_);
        k_trs<<<dim3(512, 8), 256, 0, stream>>>(x, xh, xl);
        k_gemm1t<<<512, 256, 0, stream>>>(xh, xl, Wg1, part, XD_ / 16);
        k_red1<<<256, 256, 0, stream>>>(part, bg1, Gh, Gl, 16);
        k_gemm2m<<<512, 256, 0, stream>>>(Gh, Gl, Wg2, part2);
        k_red2<<<128, 256, 0, stream>>>(part2, bg2, hh, hl);
        k_hwh_t<<<dim3(64, 8), 256, 0, stream>>>(hh, hl, whh, whl, hWh);
        k_heads<<<dim3(64, 8), 256, 0, stream>>>(hWh, z, perm, Wz, b1, w2h, w2l,
                                                 b2, W3, b3, jpart, epart);
        k_final<<<1, 64, 0, stream>>>(jpart, epart, out);
    } else {
        // Fallback: fused gather path (no pre-split planes)
        int nks = (ws_size >= (size_t)32 * PART_SLICE + 3145728 + 4096) ? 32 : 16;
        const int KS = XD_ / nks;
        const size_t partBytes = (size_t)nks * PART_SLICE;

        float* part  = (float*)base;
        float* hWh   = (float*)base;
        float* part2 = (float*)(base + 16777216);
        ushort* Gh   = (ushort*)(base + partBytes);
        ushort* Gl   = Gh + 524288;
        ushort* hh   = (ushort*)(base + partBytes + 2097152);
        ushort* hl   = hh + 262144;
        float* jpart = (float*)(base + partBytes + 3145728);
        float* epart = jpart + 512;

        k_gemm1m<<<dim3(8, 4, nks), 256, 0, stream>>>(x, Wg1, part, KS);
        k_red1<<<256, 256, 0, stream>>>(part, bg1, Gh, Gl, nks);
        k_gemm2m<<<512, 256, 0, stream>>>(Gh, Gl, Wg2, part2);
        k_red2<<<128, 256, 0, stream>>>(part2, bg2, hh, hl);
        k_hwh_f<<<dim3(64, 8), 256, 0, stream>>>(hh, hl, Wh, hWh);
        k_heads_f<<<dim3(64, 8), 256, 0, stream>>>(hWh, z, perm, Wz, b1, W2, b2,
                                                   W3, b3, jpart, epart);
        k_final<<<1, 64, 0, stream>>>(jpart, epart, out);
    }
}

// Round 14
// 407.256 us; speedup vs baseline: 1.0304x; 1.0304x over previous
//
#include <hip/hip_runtime.h>
#include <hip/hip_bf16.h>
#include <math.h>

// Problem constants
#define B_  512
#define XD_ 32768
#define PD_ 512
#define D_  64
#define H_  128
#define G1_ 1024

typedef __attribute__((ext_vector_type(8))) short short8v;
typedef __attribute__((ext_vector_type(4))) float floatx4;

__device__ __forceinline__ float eluf(float v) { return v > 0.f ? v : expm1f(v); }

// Truncation split: hi = c with low 16 mantissa bits zeroed (exact residual),
// lo = bf16-trunc of residual. Packed pairwise with v_perm_b32 (~3 ops/value).
__device__ __forceinline__ void split8t(const float* c, short8v& h, short8v& l) {
    unsigned hu[8], lu[8];
    #pragma unroll
    for (int j = 0; j < 8; j++) {
        unsigned u = __float_as_uint(c[j]);
        hu[j] = u & 0xFFFF0000u;
        float res = c[j] - __uint_as_float(hu[j]);
        lu[j] = __float_as_uint(res);
    }
    uint4 hp, lp;
    hp.x = __builtin_amdgcn_perm(hu[1], hu[0], 0x07060302u);
    hp.y = __builtin_amdgcn_perm(hu[3], hu[2], 0x07060302u);
    hp.z = __builtin_amdgcn_perm(hu[5], hu[4], 0x07060302u);
    hp.w = __builtin_amdgcn_perm(hu[7], hu[6], 0x07060302u);
    lp.x = __builtin_amdgcn_perm(lu[1], lu[0], 0x07060302u);
    lp.y = __builtin_amdgcn_perm(lu[3], lu[2], 0x07060302u);
    lp.z = __builtin_amdgcn_perm(lu[5], lu[4], 0x07060302u);
    lp.w = __builtin_amdgcn_perm(lu[7], lu[6], 0x07060302u);
    h = __builtin_bit_cast(short8v, hp);
    l = __builtin_bit_cast(short8v, lp);
}

// ---------------------------------------------------------------------------
// K0: transpose+split x[512,32768] -> xh/xl planes, layout [XD/8][B][8] ushort.
// grid (512, 8), 256 thr. LDS-tiled: coalesced reads + coalesced writes.
// ---------------------------------------------------------------------------
__global__ __launch_bounds__(256) void k_trs(const float* __restrict__ x,
                                             ushort* __restrict__ xh,
                                             ushort* __restrict__ xl) {
    __shared__ float tile[64][65];
    const int k0 = blockIdx.x * 64;
    const int m0 = blockIdx.y * 64;
    const int t = threadIdx.x;
    const int c = t & 63, rr = t >> 6;   // read: col c, row group rr
    #pragma unroll
    for (int i = 0; i < 16; i++) {
        int r = i * 4 + rr;
        tile[r][c] = x[(size_t)(m0 + r) * XD_ + k0 + c];
    }
    __syncthreads();
    const int m = t & 63;
    const int kq = t >> 6;               // 0..3
    #pragma unroll
    for (int i = 0; i < 2; i++) {
        int kg = kq * 2 + i;             // 0..7
        float cc[8];
        #pragma unroll
        for (int j = 0; j < 8; j++) cc[j] = tile[m][kg * 8 + j];
        short8v h, l; split8t(cc, h, l);
        size_t off = ((size_t)((k0 >> 3) + kg) * B_ + m0 + m) * 8;
        *(short8v*)(xh + off) = h;
        *(short8v*)(xl + off) = l;
    }
}

// ---------------------------------------------------------------------------
// K1: split-bf16 MFMA GEMM from pre-split planes (proven structure). Tile
// 128x128 (4 waves 2x2, acc[4][4]), BK=32, 1D grid 512 = 2 blocks/CU.
// T1 XCD swizzle (verified: FETCH 353->104 MB): wid = (bid%8)*64 + bid/8.
// Double-buffered LDS (64 KB), one raw lgkmcnt barrier per K-step; 2-step
// register prefetch flies across the barrier.
// ---------------------------------------------------------------------------
__global__ __launch_bounds__(256, 2) void k_gemm1t(const ushort* __restrict__ xh,
                                                   const ushort* __restrict__ xl,
                                                   const float* __restrict__ Wg1,
                                                   float* __restrict__ part,
                                                   int KS) {
    __shared__ ushort Ah[2][4 * 128 * 8], Al[2][4 * 128 * 8];
    __shared__ ushort Bh[2][4 * 128 * 8], Bl[2][4 * 128 * 8];
    const int wid = (blockIdx.x & 7) * 64 + (blockIdx.x >> 3);  // bijective (512%8==0)
    const int nt = wid & 7, mt = (wid >> 3) & 3, ks = wid >> 5;
    const int t = threadIdx.x;
    const int w = t >> 6, lane = t & 63;
    const int q = lane >> 4, l15 = lane & 15;
    const int wr = w >> 1, wc = w & 1;      // wave -> 64x64 quadrant
    const int q4 = t >> 6, pr = t & 63;     // staging: k-group, row/col id
    const int k0 = ks * KS;

    const size_t aoff = (((size_t)(k0 >> 3) + q4) * B_ + mt * 128 + pr) * 8;
    const ushort* Agh = xh + aoff;
    const ushort* Agl = xl + aoff;
    const float*  Bg  = Wg1 + (size_t)(k0 + q4 * 8) * G1_ + nt * 128 + pr * 2;

    floatx4 acc[4][4];
    #pragma unroll
    for (int i = 0; i < 4; i++)
        #pragma unroll
        for (int j = 0; j < 4; j++) acc[i][j] = (floatx4){0.f, 0.f, 0.f, 0.f};

    uint4 pAh0, pAh1, pAl0, pAl1;
    float2 pb[8];

    auto loadT = [&](int kt) {
        size_t o = (size_t)kt * B_;
        pAh0 = *(const uint4*)(Agh + o);
        pAh1 = *(const uint4*)(Agh + o + 512);
        pAl0 = *(const uint4*)(Agl + o);
        pAl1 = *(const uint4*)(Agl + o + 512);
        const float* p = Bg + (size_t)kt * G1_;
        #pragma unroll
        for (int kk = 0; kk < 8; kk++) pb[kk] = *(const float2*)(p + (size_t)kk * G1_);
    };

    auto stage = [&](int buf) {
        float c0[8], c1[8];
        #pragma unroll
        for (int kk = 0; kk < 8; kk++) { c0[kk] = pb[kk].x; c1[kk] = pb[kk].y; }
        short8v bh0, bl0, bh1, bl1;
        split8t(c0, bh0, bl0); split8t(c1, bh1, bl1);
        int n0 = pr * 2;
        int i0 = (q4 * 128 + (n0 ^ q4)) * 8;
        int i1 = (q4 * 128 + ((n0 + 1) ^ q4)) * 8;
        *(short8v*)&Bh[buf][i0] = bh0; *(short8v*)&Bl[buf][i0] = bl0;
        *(short8v*)&Bh[buf][i1] = bh1; *(short8v*)&Bl[buf][i1] = bl1;
        int ia = (q4 * 128 + (pr ^ q4)) * 8;
        *(uint4*)&Ah[buf][ia] = pAh0;
        *(uint4*)&Al[buf][ia] = pAl0;
        *(uint4*)&Ah[buf][ia + 512] = pAh1;
        *(uint4*)&Al[buf][ia + 512] = pAl1;
    };

    auto mma = [&](int buf) {
        short8v af[4], alf[4], bf[4], blf[4];
        #pragma unroll
        for (int i = 0; i < 4; i++) {
            int m = wr * 64 + i * 16 + l15;
            int idx = (q * 128 + (m ^ q)) * 8;
            af[i]  = *(const short8v*)&Ah[buf][idx];
            alf[i] = *(const short8v*)&Al[buf][idx];
        }
        #pragma unroll
        for (int j = 0; j < 4; j++) {
            int n = wc * 64 + j * 16 + l15;
            int idx = (q * 128 + (n ^ q)) * 8;
            bf[j]  = *(const short8v*)&Bh[buf][idx];
            blf[j] = *(const short8v*)&Bl[buf][idx];
        }
        #pragma unroll
        for (int i = 0; i < 4; i++)
            #pragma unroll
            for (int j = 0; j < 4; j++) {
                acc[i][j] = __builtin_amdgcn_mfma_f32_16x16x32_bf16(af[i],  bf[j],  acc[i][j], 0, 0, 0);
                acc[i][j] = __builtin_amdgcn_mfma_f32_16x16x32_bf16(af[i],  blf[j], acc[i][j], 0, 0, 0);
                acc[i][j] = __builtin_amdgcn_mfma_f32_16x16x32_bf16(alf[i], bf[j],  acc[i][j], 0, 0, 0);
            }
    };

    loadT(0);
    stage(0);
    loadT(32);
    asm volatile("s_waitcnt lgkmcnt(0)" ::: "memory");
    __builtin_amdgcn_s_barrier();

    const int NT = KS >> 5;
    for (int it = 0; it < NT - 1; it++) {
        const int cur = it & 1;
        stage(cur ^ 1);
        if (it + 2 < NT) loadT((it + 2) * 32);
        mma(cur);
        asm volatile("s_waitcnt lgkmcnt(0)" ::: "memory");
        __builtin_amdgcn_s_barrier();
    }
    mma((NT - 1) & 1);

    float* P = part + (size_t)ks * (B_ * G1_) + (size_t)(mt * 128) * G1_ + nt * 128;
    #pragma unroll
    for (int i = 0; i < 4; i++)
        #pragma unroll
        for (int j = 0; j < 4; j++) {
            int col = wc * 64 + j * 16 + l15;
            #pragma unroll
            for (int r = 0; r < 4; r++) {
                int row = wr * 64 + i * 16 + q * 4 + r;
                P[(size_t)row * G1_ + col] = acc[i][j][r];
            }
        }
}

// ---------------------------------------------------------------------------
// K1 (fallback, small workspace): fused gather version reading x directly.
// ---------------------------------------------------------------------------
__global__ __launch_bounds__(256, 2) void k_gemm1m(const float* __restrict__ x,
                                                   const float* __restrict__ Wg1,
                                                   float* __restrict__ part,
                                                   int KS) {
    __shared__ ushort Ah[4 * 128 * 8], Al[4 * 128 * 8];
    __shared__ ushort Bh[4 * 128 * 8], Bl[4 * 128 * 8];
    const int nt = blockIdx.x, mt = blockIdx.y, ks = blockIdx.z;
    const int t = threadIdx.x;
    const int w = t >> 6, lane = t & 63;
    const int q = lane >> 4, l15 = lane & 15;
    const int wr = w >> 1, wc = w & 1;
    const int kbB = t >> 6, nb = t & 63;
    const int mA = t & 127, kbA = t >> 7;
    const int k0 = ks * KS;

    const float* Ag = x + (size_t)(mt * 128 + mA) * XD_ + k0 + kbA * 8;
    const float* Bg = Wg1 + (size_t)(k0 + kbB * 8) * G1_ + nt * 128 + nb * 2;

    floatx4 acc[4][4];
    #pragma unroll
    for (int i = 0; i < 4; i++)
        #pragma unroll
        for (int j = 0; j < 4; j++) acc[i][j] = (floatx4){0.f, 0.f, 0.f, 0.f};

    float4 pa0 = *(const float4*)(Ag);
    float4 pa1 = *(const float4*)(Ag + 4);
    float4 pa2 = *(const float4*)(Ag + 16);
    float4 pa3 = *(const float4*)(Ag + 20);
    float2 pb[8];
    #pragma unroll
    for (int kk = 0; kk < 8; kk++) pb[kk] = *(const float2*)(Bg + (size_t)kk * G1_);

    for (int kt = 0; kt < KS; kt += 32) {
        float cA0[8] = {pa0.x, pa0.y, pa0.z, pa0.w, pa1.x, pa1.y, pa1.z, pa1.w};
        float cA1[8] = {pa2.x, pa2.y, pa2.z, pa2.w, pa3.x, pa3.y, pa3.z, pa3.w};
        float c0[8], c1[8];
        #pragma unroll
        for (int kk = 0; kk < 8; kk++) { c0[kk] = pb[kk].x; c1[kk] = pb[kk].y; }
        short8v ah0, al0, ah1, al1, bh0, bl0, bh1, bl1;
        split8t(cA0, ah0, al0);
        split8t(cA1, ah1, al1);
        split8t(c0, bh0, bl0);
        split8t(c1, bh1, bl1);
        if (kt + 32 < KS) {
            pa0 = *(const float4*)(Ag + kt + 32);
            pa1 = *(const float4*)(Ag + kt + 36);
            pa2 = *(const float4*)(Ag + kt + 48);
            pa3 = *(const float4*)(Ag + kt + 52);
            const float* p = Bg + (size_t)(kt + 32) * G1_;
            #pragma unroll
            for (int kk = 0; kk < 8; kk++) pb[kk] = *(const float2*)(p + (size_t)kk * G1_);
        }
        {
            int ia0 = (kbA * 128 + (mA ^ kbA)) * 8;
            int ia1 = ((kbA + 2) * 128 + (mA ^ (kbA + 2))) * 8;
            *(short8v*)&Ah[ia0] = ah0; *(short8v*)&Al[ia0] = al0;
            *(short8v*)&Ah[ia1] = ah1; *(short8v*)&Al[ia1] = al1;
            int n0i = nb * 2;
            int i0 = (kbB * 128 + (n0i ^ kbB)) * 8;
            int i1 = (kbB * 128 + ((n0i + 1) ^ kbB)) * 8;
            *(short8v*)&Bh[i0] = bh0; *(short8v*)&Bl[i0] = bl0;
            *(short8v*)&Bh[i1] = bh1; *(short8v*)&Bl[i1] = bl1;
        }
        __syncthreads();
        short8v af[4], alf[4], bf[4], blf[4];
        #pragma unroll
        for (int i = 0; i < 4; i++) {
            int m = wr * 64 + i * 16 + l15;
            int idx = (q * 128 + (m ^ q)) * 8;
            af[i]  = *(const short8v*)&Ah[idx];
            alf[i] = *(const short8v*)&Al[idx];
        }
        #pragma unroll
        for (int j = 0; j < 4; j++) {
            int n = wc * 64 + j * 16 + l15;
            int idx = (q * 128 + (n ^ q)) * 8;
            bf[j]  = *(const short8v*)&Bh[idx];
            blf[j] = *(const short8v*)&Bl[idx];
        }
        #pragma unroll
        for (int i = 0; i < 4; i++)
            #pragma unroll
            for (int j = 0; j < 4; j++) {
                acc[i][j] = __builtin_amdgcn_mfma_f32_16x16x32_bf16(af[i],  bf[j],  acc[i][j], 0, 0, 0);
                acc[i][j] = __builtin_amdgcn_mfma_f32_16x16x32_bf16(af[i],  blf[j], acc[i][j], 0, 0, 0);
                acc[i][j] = __builtin_amdgcn_mfma_f32_16x16x32_bf16(alf[i], bf[j],  acc[i][j], 0, 0, 0);
            }
        __syncthreads();
    }
    float* P = part + (size_t)ks * (B_ * G1_) + (size_t)(mt * 128) * G1_ + nt * 128;
    #pragma unroll
    for (int i = 0; i < 4; i++)
        #pragma unroll
        for (int j = 0; j < 4; j++) {
            int col = wc * 64 + j * 16 + l15;
            #pragma unroll
            for (int r = 0; r < 4; r++) {
                int row = wr * 64 + i * 16 + q * 4 + r;
                P[(size_t)row * G1_ + col] = acc[i][j][r];
            }
        }
}

// K1b: reduce nparts split-K partials + bias + elu -> G as bf16 hi/lo planes
__global__ __launch_bounds__(256) void k_red1(const float* __restrict__ part,
                                              const float* __restrict__ bg1,
                                              ushort* __restrict__ Gh,
                                              ushort* __restrict__ Gl,
                                              int nparts) {
    int idx = (blockIdx.x * 256 + threadIdx.x) * 8;  // 524288 total / 8
    const int S = B_ * G1_;
    float c[8] = {};
    for (int k = 0; k < nparts; k++) {
        const float* p = part + (size_t)k * S + idx;
        float4 v0 = *(const float4*)p, v1 = *(const float4*)(p + 4);
        c[0] += v0.x; c[1] += v0.y; c[2] += v0.z; c[3] += v0.w;
        c[4] += v1.x; c[5] += v1.y; c[6] += v1.z; c[7] += v1.w;
    }
    int cb = idx & (G1_ - 1);
    float4 b0 = *(const float4*)(bg1 + cb), b1v = *(const float4*)(bg1 + cb + 4);
    c[0] = eluf(c[0] + b0.x); c[1] = eluf(c[1] + b0.y);
    c[2] = eluf(c[2] + b0.z); c[3] = eluf(c[3] + b0.w);
    c[4] = eluf(c[4] + b1v.x); c[5] = eluf(c[5] + b1v.y);
    c[6] = eluf(c[6] + b1v.z); c[7] = eluf(c[7] + b1v.w);
    short8v h, l; split8t(c, h, l);
    *(short8v*)(Gh + idx) = h;
    *(short8v*)(Gl + idx) = l;
}

// ---------------------------------------------------------------------------
// K2: part2[ks] = G[512,1024] @ Wg2[1024,512] slice — split-bf16 MFMA.
// 1D grid 512 with T1 XCD swizzle. dbuf + register prefetch + single raw
// lgkmcnt barrier per K-step.
// ---------------------------------------------------------------------------
__global__ __launch_bounds__(256, 2) void k_gemm2m(const ushort* __restrict__ Gh,
                                                   const ushort* __restrict__ Gl,
                                                   const float* __restrict__ Wg2,
                                                   float* __restrict__ part2) {
    __shared__ ushort Ah[2][4 * 64 * 8], Al[2][4 * 64 * 8];   // 4 KB each buf
    __shared__ ushort Bh[2][4 * 64 * 8], Bl[2][4 * 64 * 8];
    const int wid = (blockIdx.x & 7) * 64 + (blockIdx.x >> 3);
    const int nt = wid & 7, mt = (wid >> 3) & 7, ks = wid >> 6;
    const int t = threadIdx.x;
    const int w = t >> 6, lane = t & 63;
    const int q = lane >> 4, l15 = lane & 15;
    const int kb = (t >> 4) & 3;
    const int rb = (t & 15) | (w << 4);
    const int k0 = ks * 128;
    const int cB = t & 63, g = t >> 6;

    floatx4 acc[4];
    #pragma unroll
    for (int i = 0; i < 4; i++) acc[i] = (floatx4){0.f, 0.f, 0.f, 0.f};

    uint4 pAh, pAl;
    float cb8[8];

    auto loadT = [&](int kt) {
        const ushort* pH = Gh + (size_t)(mt * 64 + rb) * G1_ + k0 + kt + kb * 8;
        const ushort* pL = Gl + (size_t)(mt * 64 + rb) * G1_ + k0 + kt + kb * 8;
        pAh = *(const uint4*)pH;
        pAl = *(const uint4*)pL;
        const float* p = Wg2 + (size_t)(k0 + kt + g * 8) * PD_ + nt * 64 + cB;
        #pragma unroll
        for (int kk = 0; kk < 8; kk++) cb8[kk] = p[(size_t)kk * PD_];
    };

    auto stage = [&](int buf) {
        int ia = (kb * 64 + (rb ^ kb)) * 8;
        *(uint4*)&Ah[buf][ia] = pAh;
        *(uint4*)&Al[buf][ia] = pAl;
        short8v h, l; split8t(cb8, h, l);
        int ib = (g * 64 + (cB ^ g)) * 8;
        *(short8v*)&Bh[buf][ib] = h;
        *(short8v*)&Bl[buf][ib] = l;
    };

    auto mma = [&](int buf) {
        short8v af[4], alf[4], bf, blf;
        #pragma unroll
        for (int i = 0; i < 4; i++) {
            int m = i * 16 + l15;
            int idx = (q * 64 + (m ^ q)) * 8;
            af[i]  = *(const short8v*)&Ah[buf][idx];
            alf[i] = *(const short8v*)&Al[buf][idx];
        }
        {
            int n = w * 16 + l15;
            int idx = (q * 64 + (n ^ q)) * 8;
            bf  = *(const short8v*)&Bh[buf][idx];
            blf = *(const short8v*)&Bl[buf][idx];
        }
        #pragma unroll
        for (int i = 0; i < 4; i++) {
            acc[i] = __builtin_amdgcn_mfma_f32_16x16x32_bf16(af[i],  bf,  acc[i], 0, 0, 0);
            acc[i] = __builtin_amdgcn_mfma_f32_16x16x32_bf16(af[i],  blf, acc[i], 0, 0, 0);
            acc[i] = __builtin_amdgcn_mfma_f32_16x16x32_bf16(alf[i], bf,  acc[i], 0, 0, 0);
        }
    };

    loadT(0);
    stage(0);
    loadT(32);
    asm volatile("s_waitcnt lgkmcnt(0)" ::: "memory");
    __builtin_amdgcn_s_barrier();

    for (int it = 0; it < 3; it++) {
        const int cur = it & 1;
        stage(cur ^ 1);
        if (it + 2 < 4) loadT((it + 2) * 32);
        mma(cur);
        asm volatile("s_waitcnt lgkmcnt(0)" ::: "memory");
        __builtin_amdgcn_s_barrier();
    }
    mma(1);

    float* P = part2 + (size_t)ks * (B_ * PD_) + (size_t)(mt * 64) * PD_ + nt * 64;
    #pragma unroll
    for (int i = 0; i < 4; i++) {
        int col = w * 16 + l15;
        #pragma unroll
        for (int r = 0; r < 4; r++) {
            int row = i * 16 + q * 4 + r;
            P[(size_t)row * PD_ + col] = acc[i][r];
        }
    }
}

// K2b: reduce 8 partials + bias + elu -> h as bf16 hi/lo planes
__global__ __launch_bounds__(256) void k_red2(const float* __restrict__ part2,
                                              const float* __restrict__ bg2,
                                              ushort* __restrict__ hh,
                                              ushort* __restrict__ hl) {
    int idx = (blockIdx.x * 256 + threadIdx.x) * 8;
    const int S = B_ * PD_;
    float c[8] = {};
    #pragma unroll
    for (int k = 0; k < 8; k++) {
        const float* p = part2 + (size_t)k * S + idx;
        float4 v0 = *(const float4*)p, v1 = *(const float4*)(p + 4);
        c[0] += v0.x; c[1] += v0.y; c[2] += v0.z; c[3] += v0.w;
        c[4] += v1.x; c[5] += v1.y; c[6] += v1.z; c[7] += v1.w;
    }
    int cb = idx & (PD_ - 1);
    float4 b0 = *(const float4*)(bg2 + cb), b1v = *(const float4*)(bg2 + cb + 4);
    c[0] = eluf(c[0] + b0.x); c[1] = eluf(c[1] + b0.y);
    c[2] = eluf(c[2] + b0.z); c[3] = eluf(c[3] + b0.w);
    c[4] = eluf(c[4] + b1v.x); c[5] = eluf(c[5] + b1v.y);
    c[6] = eluf(c[6] + b1v.z); c[7] = eluf(c[7] + b1v.w);
    short8v h, l; split8t(c, h, l);
    *(short8v*)(hh + idx) = h;
    *(short8v*)(hl + idx) = l;
}

// ---------------------------------------------------------------------------
// K3: hWh[b,d,h] = sum_p h[b,p] * Wh[d,p,h] — split-bf16 MFMA, tile 64x128,
// grid (64 d, 8 mt) = 512 blocks = 2/CU (flat%8 = d%8 -> Wh L2 reuse).
// dbuf + single raw lgkmcnt barrier.
// ---------------------------------------------------------------------------
__global__ __launch_bounds__(256, 2) void k_hwh_t(const ushort* __restrict__ hh,
                                                  const ushort* __restrict__ hl,
                                                  const float* __restrict__ Wh,
                                                  float* __restrict__ hWh) {
    __shared__ ushort Ah[2][4 * 64 * 8], Al[2][4 * 64 * 8];
    __shared__ ushort Bh[2][4 * 128 * 8], Bl[2][4 * 128 * 8];
    const int d = blockIdx.x, mt = blockIdx.y;
    const int t = threadIdx.x;
    const int w = t >> 6, lane = t & 63;
    const int q = lane >> 4, l15 = lane & 15;
    const int kb = (t >> 4) & 3;
    const int rb = (t & 15) | (w << 4);
    const int kgB = t >> 6, pr = t & 63;

    const ushort* AgH = hh + (size_t)(mt * 64 + rb) * PD_ + kb * 8;
    const ushort* AgL = hl + (size_t)(mt * 64 + rb) * PD_ + kb * 8;
    const float* Bg = Wh + (size_t)d * (PD_ * H_) + (size_t)(kgB * 8) * H_ + pr * 2;

    floatx4 acc[4][2];
    #pragma unroll
    for (int i = 0; i < 4; i++)
        #pragma unroll
        for (int j = 0; j < 2; j++) acc[i][j] = (floatx4){0.f, 0.f, 0.f, 0.f};

    uint4 pah, pal;
    float2 pb[8];

    auto loadT = [&](int kt) {
        pah = *(const uint4*)(AgH + kt);
        pal = *(const uint4*)(AgL + kt);
        const float* p = Bg + (size_t)kt * H_;
        #pragma unroll
        for (int kk = 0; kk < 8; kk++) pb[kk] = *(const float2*)(p + (size_t)kk * H_);
    };

    auto stage = [&](int buf) {
        float c0[8], c1[8];
        #pragma unroll
        for (int kk = 0; kk < 8; kk++) { c0[kk] = pb[kk].x; c1[kk] = pb[kk].y; }
        short8v bh0, bl0, bh1, bl1;
        split8t(c0, bh0, bl0); split8t(c1, bh1, bl1);
        int n0 = pr * 2;
        int i0 = (kgB * 128 + (n0 ^ kgB)) * 8;
        int i1 = (kgB * 128 + ((n0 + 1) ^ kgB)) * 8;
        *(short8v*)&Bh[buf][i0] = bh0; *(short8v*)&Bl[buf][i0] = bl0;
        *(short8v*)&Bh[buf][i1] = bh1; *(short8v*)&Bl[buf][i1] = bl1;
        int ia = (kb * 64 + (rb ^ kb)) * 8;
        *(uint4*)&Ah[buf][ia] = pah;
        *(uint4*)&Al[buf][ia] = pal;
    };

    auto mma = [&](int buf) {
        short8v af[4], alf[4], bf[2], blf[2];
        #pragma unroll
        for (int i = 0; i < 4; i++) {
            int m = i * 16 + l15;
            int idx = (q * 64 + (m ^ q)) * 8;
            af[i]  = *(const short8v*)&Ah[buf][idx];
            alf[i] = *(const short8v*)&Al[buf][idx];
        }
        #pragma unroll
        for (int j = 0; j < 2; j++) {
            int n = w * 32 + j * 16 + l15;
            int idx = (q * 128 + (n ^ q)) * 8;
            bf[j]  = *(const short8v*)&Bh[buf][idx];
            blf[j] = *(const short8v*)&Bl[buf][idx];
        }
        #pragma unroll
        for (int i = 0; i < 4; i++)
            #pragma unroll
            for (int j = 0; j < 2; j++) {
                acc[i][j] = __builtin_amdgcn_mfma_f32_16x16x32_bf16(af[i],  bf[j],  acc[i][j], 0, 0, 0);
                acc[i][j] = __builtin_amdgcn_mfma_f32_16x16x32_bf16(af[i],  blf[j], acc[i][j], 0, 0, 0);
                acc[i][j] = __builtin_amdgcn_mfma_f32_16x16x32_bf16(alf[i], bf[j],  acc[i][j], 0, 0, 0);
            }
    };

    loadT(0);
    stage(0);
    loadT(32);
    asm volatile("s_waitcnt lgkmcnt(0)" ::: "memory");
    __builtin_amdgcn_s_barrier();

    const int NT = PD_ >> 5;               // 16
    for (int it = 0; it < NT - 1; it++) {
        const int cur = it & 1;
        stage(cur ^ 1);
        if (it + 2 < NT) loadT((it + 2) * 32);
        mma(cur);
        asm volatile("s_waitcnt lgkmcnt(0)" ::: "memory");
        __builtin_amdgcn_s_barrier();
    }
    mma((NT - 1) & 1);

    #pragma unroll
    for (int i = 0; i < 4; i++)
        #pragma unroll
        for (int j = 0; j < 2; j++) {
            int col = w * 32 + j * 16 + l15;
            #pragma unroll
            for (int r = 0; r < 4; r++) {
                int row = i * 16 + q * 4 + r;
                int b = mt * 64 + row;
                hWh[(size_t)b * (D_ * H_) + d * H_ + col] = acc[i][j][r];
            }
        }
}

// ---------------------------------------------------------------------------
// K4: heads — split-bf16 MFMA. grid (64 d, 8 chunk): flat%8 = d%8 puts all
// 8 chunk-blocks of a d on ONE XCD -> W2[d] L2-local. 2 passes FUSED.
// W2 dbuf + register prefetch + single raw lgkmcnt barrier per kt2.
// sred aliases A1h. LDS 65 KB -> 2 blocks/CU.
// ---------------------------------------------------------------------------
__global__ __launch_bounds__(256, 2) void k_heads(const float* __restrict__ hWh,
                                                  const float* __restrict__ z,
                                                  const int* __restrict__ perm,
                                                  const float* __restrict__ Wz,
                                                  const float* __restrict__ b1,
                                                  const float* __restrict__ W2,
                                                  const float* __restrict__ b2,
                                                  const float* __restrict__ W3,
                                                  const float* __restrict__ b3,
                                                  float* __restrict__ jpart,
                                                  float* __restrict__ epart) {
    const int d = blockIdx.x;       // 0..63
    const int chunk = blockIdx.y;   // 0..7
    const int t = threadIdx.x;
    const int b0 = chunk * 64;
    __shared__ ushort A1h[16 * 64 * 8];       // 16 KB (aliased as sred)
    __shared__ ushort A1l[16 * 64 * 8];       // 16 KB
    __shared__ ushort B2h[2][4 * 128 * 8];    // 8 KB each buf
    __shared__ ushort B2l[2][4 * 128 * 8];    // 8 KB each buf
    __shared__ float  sq[4][64];              // 1 KB
    float* sred = (float*)A1h;                // [64][64]

    const int w = t >> 6, lane = t & 63;
    const int q = lane >> 4, l15 = lane & 15;
    const int kb = (t >> 4) & 3;
    const int rb = (t & 15) | (w << 4);

    const float* W2d = W2 + (size_t)d * H_ * H_;
    const float* Wzd = Wz + d * H_;
    const float* b1d = b1 + d * H_;
    const float* b2d = b2 + d * H_;
    const float* W3d = W3 + d * H_;

    float2 pbW[8];
    auto loadW2 = [&](int kt2) {
        const float* p = W2d + (size_t)(kt2 * 32 + kb * 8) * H_ + rb * 2;
        #pragma unroll
        for (int kk = 0; kk < 8; kk++) pbW[kk] = *(const float2*)(p + (size_t)kk * H_);
    };
    auto stageB = [&](int buf) {
        float c0[8], c1[8];
        #pragma unroll
        for (int kk = 0; kk < 8; kk++) { c0[kk] = pbW[kk].x; c1[kk] = pbW[kk].y; }
        short8v h0v, l0v, h1v, l1v;
        split8t(c0, h0v, l0v);
        split8t(c1, h1v, l1v);
        int n0i = rb * 2;
        int i0 = (kb * 128 + (n0i ^ kb)) * 8;
        int i1 = (kb * 128 + ((n0i + 1) ^ kb)) * 8;
        *(short8v*)&B2h[buf][i0] = h0v; *(short8v*)&B2l[buf][i0] = l0v;
        *(short8v*)&B2h[buf][i1] = h1v; *(short8v*)&B2l[buf][i1] = l1v;
    };

    float result0 = 0.f, result1 = 0.f;
    for (int pass = 0; pass < 2; pass++) {
        // ---- build a1 (split) into A-fragment LDS layout
        {
            int i = t >> 2;
            int kt = t & 3;
            int h0 = kt * 32;
            int bb = b0 + i;
            int src = (pass == 0) ? bb : perm[bb];
            float zv = z[bb * D_ + d];
            const float* hrow = hWh + (size_t)src * (D_ * H_) + d * H_;
            #pragma unroll
            for (int kq = 0; kq < 4; kq++) {
                float c[8];
                int kbase = h0 + kq * 8;
                float4 v0 = *(const float4*)(hrow + kbase);
                float4 v1 = *(const float4*)(hrow + kbase + 4);
                float4 w0 = *(const float4*)(Wzd + kbase);
                float4 w1 = *(const float4*)(Wzd + kbase + 4);
                float4 x0 = *(const float4*)(b1d + kbase);
                float4 x1 = *(const float4*)(b1d + kbase + 4);
                c[0] = eluf(v0.x + zv * w0.x + x0.x);
                c[1] = eluf(v0.y + zv * w0.y + x0.y);
                c[2] = eluf(v0.z + zv * w0.z + x0.z);
                c[3] = eluf(v0.w + zv * w0.w + x0.w);
                c[4] = eluf(v1.x + zv * w1.x + x1.x);
                c[5] = eluf(v1.y + zv * w1.y + x1.y);
                c[6] = eluf(v1.z + zv * w1.z + x1.z);
                c[7] = eluf(v1.w + zv * w1.w + x1.w);
                short8v hv, lv; split8t(c, hv, lv);
                int idx = ((kt * 4 + kq) * 64 + (i ^ kq)) * 8;
                *(short8v*)&A1h[idx] = hv;
                *(short8v*)&A1l[idx] = lv;
            }
        }
        // ---- K pipeline prologue: stage kt2=0, prefetch kt2=1
        loadW2(0);
        stageB(0);
        loadW2(1);
        asm volatile("s_waitcnt lgkmcnt(0)" ::: "memory");
        __builtin_amdgcn_s_barrier();

        floatx4 acc[4][2];
        #pragma unroll
        for (int i = 0; i < 4; i++)
            #pragma unroll
            for (int j = 0; j < 2; j++) acc[i][j] = (floatx4){0.f, 0.f, 0.f, 0.f};

        auto mmaP = [&](int buf, int kt2) {
            short8v af[4], alf[4], bf[2], blf[2];
            #pragma unroll
            for (int i = 0; i < 4; i++) {
                int m = i * 16 + l15;
                int idx = ((kt2 * 4 + q) * 64 + (m ^ q)) * 8;
                af[i]  = *(const short8v*)&A1h[idx];
                alf[i] = *(const short8v*)&A1l[idx];
            }
            #pragma unroll
            for (int j = 0; j < 2; j++) {
                int n = w * 32 + j * 16 + l15;
                int idx = (q * 128 + (n ^ q)) * 8;
                bf[j]  = *(const short8v*)&B2h[buf][idx];
                blf[j] = *(const short8v*)&B2l[buf][idx];
            }
            #pragma unroll
            for (int i = 0; i < 4; i++)
                #pragma unroll
                for (int j = 0; j < 2; j++) {
                    acc[i][j] = __builtin_amdgcn_mfma_f32_16x16x32_bf16(af[i],  bf[j],  acc[i][j], 0, 0, 0);
                    acc[i][j] = __builtin_amdgcn_mfma_f32_16x16x32_bf16(af[i],  blf[j], acc[i][j], 0, 0, 0);
                    acc[i][j] = __builtin_amdgcn_mfma_f32_16x16x32_bf16(alf[i], bf[j],  acc[i][j], 0, 0, 0);
                }
        };

        for (int kt2 = 0; kt2 < 3; kt2++) {
            const int cur = kt2 & 1;
            stageB(cur ^ 1);                  // stage kt2+1
            if (kt2 + 2 < 4) loadW2(kt2 + 2);
            mmaP(cur, kt2);
            asm volatile("s_waitcnt lgkmcnt(0)" ::: "memory");
            __builtin_amdgcn_s_barrier();
        }
        mmaP(1, 3);
        __syncthreads();   // all frag reads (incl. A1h) done before sred writes

        // ---- epilogue: a2 = elu(acc + b2), partial score = sum a2*W3
        #pragma unroll
        for (int i = 0; i < 4; i++) {
            #pragma unroll
            for (int r = 0; r < 4; r++) {
                int b = i * 16 + q * 4 + r;
                float s = 0.f;
                #pragma unroll
                for (int j = 0; j < 2; j++) {
                    int col = w * 32 + j * 16 + l15;
                    float a2v = eluf(acc[i][j][r] + b2d[col]);
                    s = fmaf(a2v, W3d[col], s);
                }
                sred[b * 64 + w * 16 + l15] = s;
            }
        }
        __syncthreads();
        // parallel quarter-row sums: thread t -> row t&63, quarter t>>6
        {
            int rrow = t & 63, qd = t >> 6;
            const float4* rp = (const float4*)&sred[rrow * 64 + qd * 16];
            float ps = 0.f;
            #pragma unroll
            for (int c = 0; c < 4; c++) {
                float4 v = rp[c];
                ps += v.x + v.y + v.z + v.w;
            }
            sq[qd][rrow] = ps;
        }
        __syncthreads();
        float val = 0.f;
        if (t < 64) {
            float s = b3[d] + sq[0][t] + sq[1][t] + sq[2][t] + sq[3][t];
            val = (pass == 0) ? s : expf(s);
            #pragma unroll
            for (int off = 32; off > 0; off >>= 1)
                val += __shfl_down(val, off, 64);
        }
        if (t == 0) { if (pass == 0) result0 = val; else result1 = val; }
        __syncthreads();   // protect sred/A1 before next pass rebuilds
    }
    if (t == 0) {
        jpart[d * 8 + chunk] = result0;
        epart[d * 8 + chunk] = result1;
    }
}

// K5: final scalar. 1 block, 64 threads (one per d).
__global__ void k_final(const float* __restrict__ jpart,
                        const float* __restrict__ epart,
                        float* __restrict__ out) {
    int t = threadIdx.x;
    float mj = 0.f, me = 0.f;
    #pragma unroll
    for (int c = 0; c < 8; c++) { mj += jpart[t * 8 + c]; me += epart[t * 8 + c]; }
    mj *= (1.f / 512.f);
    me *= (1.f / 512.f);
    float mi = mj - logf(me);
    #pragma unroll
    for (int off = 32; off > 0; off >>= 1) mi += __shfl_down(mi, off, 64);
    if (t == 0) out[0] = -mi * (1.f / 64.f);
}

extern "C" void kernel_launch(void* const* d_in, const int* in_sizes, int n_in,
                              void* d_out, int out_size, void* d_ws, size_t ws_size,
                              hipStream_t stream) {
    const float* x   = (const float*)d_in[0];
    const float* z   = (const float*)d_in[1];
    const int*  perm = (const int*)d_in[2];
    const float* Wg1 = (const float*)d_in[3];
    const float* bg1 = (const float*)d_in[4];
    const float* Wg2 = (const float*)d_in[5];
    const float* bg2 = (const float*)d_in[6];
    const float* Wh  = (const float*)d_in[7];
    const float* Wz  = (const float*)d_in[8];
    const float* b1  = (const float*)d_in[9];
    const float* W2  = (const float*)d_in[10];
    const float* b2  = (const float*)d_in[11];
    const float* W3  = (const float*)d_in[12];
    const float* b3  = (const float*)d_in[13];
    float* out = (float*)d_out;

    char* base = (char*)d_ws;
    const size_t PART_SLICE = (size_t)B_ * G1_ * sizeof(float);   // 2 MB

    // Layout: part(16x2MB) | xh(32MB) | xl(32MB) | Gh/Gl | hh/hl | jp/ep
    const size_t NEW_NEED = 16 * PART_SLICE + 67108864ull + 2097152 + 1048576 + 4096;

    if (ws_size >= NEW_NEED) {
        float* part  = (float*)base;                       // 32 MB (16 slices)
        ushort* xh   = (ushort*)(base + 33554432);         // 32 MB
        ushort* xl   = (ushort*)(base + 67108864);         // 32 MB
        float* hWh   = (float*)base;                       // overlaps dead part
        float* part2 = (float*)(base + 16777216);
        ushort* Gh   = (ushort*)(base + 100663296);
        ushort* Gl   = Gh + 524288;
        ushort* hh   = (ushort*)(base + 102760448);
        ushort* hl   = hh + 262144;
        float* jpart = (float*)(base + 103809024);
        float* epart = jpart + 512;

        k_trs<<<dim3(512, 8), 256, 0, stream>>>(x, xh, xl);
        k_gemm1t<<<512, 256, 0, stream>>>(xh, xl, Wg1, part, XD_ / 16);
        k_red1<<<256, 256, 0, stream>>>(part, bg1, Gh, Gl, 16);
        k_gemm2m<<<512, 256, 0, stream>>>(Gh, Gl, Wg2, part2);
        k_red2<<<128, 256, 0, stream>>>(part2, bg2, hh, hl);
        k_hwh_t<<<dim3(64, 8), 256, 0, stream>>>(hh, hl, Wh, hWh);
        k_heads<<<dim3(64, 8), 256, 0, stream>>>(hWh, z, perm, Wz, b1, W2, b2, W3, b3,
                                                 jpart, epart);
        k_final<<<1, 64, 0, stream>>>(jpart, epart, out);
    } else {
        // Fallback: fused gather path
        int nks = (ws_size >= (size_t)32 * PART_SLICE + 3145728 + 4096) ? 32 : 16;
        const int KS = XD_ / nks;
        const size_t partBytes = (size_t)nks * PART_SLICE;

        float* part  = (float*)base;
        float* hWh   = (float*)base;
        float* part2 = (float*)(base + 16777216);
        ushort* Gh   = (ushort*)(base + partBytes);
        ushort* Gl   = Gh + 524288;
        ushort* hh   = (ushort*)(base + partBytes + 2097152);
        ushort* hl   = hh + 262144;
        float* jpart = (float*)(base + partBytes + 3145728);
        float* epart = jpart + 512;

        k_gemm1m<<<dim3(8, 4, nks), 256, 0, stream>>>(x, Wg1, part, KS);
        k_red1<<<256, 256, 0, stream>>>(part, bg1, Gh, Gl, nks);
        k_gemm2m<<<512, 256, 0, stream>>>(Gh, Gl, Wg2, part2);
        k_red2<<<128, 256, 0, stream>>>(part2, bg2, hh, hl);
        k_hwh_t<<<dim3(64, 8), 256, 0, stream>>>(hh, hl, Wh, hWh);
        k_heads<<<dim3(64, 8), 256, 0, stream>>>(hWh, z, perm, Wz, b1, W2, b2, W3, b3,
                                                 jpart, epart);
        k_final<<<1, 64, 0, stream>>>(jpart, epart, out);
    }
}